// Round 3
// baseline (1257.304 us; speedup 1.0000x reference)
//
#include <hip/hip_runtime.h>

// GIN forward, MI355X. Round 3:
//  - column stats fused into GEMM epilogues (shfl_xor reduce-scatter butterfly)
//  - post-BN activations never materialized: consumers apply double affine on the fly
//  - 22 dispatches (was 30); CSR build unchanged

#define HID 64
#define LAYERS 3
#define BN_EPS 1e-5f

__device__ __forceinline__ float relu_aff(float x, float s, float t) {
    return fmaxf(fmaf(x, s, t), 0.f);
}

// compute affine (s,t) for column c from raw sums
__device__ __forceinline__ void bn_fin(const float* __restrict__ raw, const float* __restrict__ g,
                                       const float* __restrict__ b, float invN, int c,
                                       float& s, float& t) {
    float m = raw[c] * invN;
    float v = fmaf(-m, m, raw[64 + c] * invN);
    float r = rsqrtf(v + BN_EPS);
    s = r * g[c];
    t = fmaf(-m, s, b[c]);
}

// ---------------- CSR build ----------------
__global__ void k_hist(const int* __restrict__ dst, int* __restrict__ cnt, int E) {
    int e = blockIdx.x * 256 + threadIdx.x;
    if (e < E) atomicAdd(&cnt[dst[e]], 1);
}

__global__ void k_scan1(const int* __restrict__ cnt, int* __restrict__ part, int n) {
    __shared__ int sm[256];
    int i = blockIdx.x * 256 + threadIdx.x;
    sm[threadIdx.x] = (i < n) ? cnt[i] : 0;
    __syncthreads();
    for (int s = 128; s > 0; s >>= 1) {
        if (threadIdx.x < s) sm[threadIdx.x] += sm[threadIdx.x + s];
        __syncthreads();
    }
    if (threadIdx.x == 0) part[blockIdx.x] = sm[0];
}

__global__ void k_scan2(int* part, int nb, int* row_off, int N) {
    int lane = threadIdx.x & 63, wid = threadIdx.x >> 6;
    int v = (threadIdx.x < nb) ? part[threadIdx.x] : 0;
    int incl = v;
    for (int d = 1; d < 64; d <<= 1) { int y = __shfl_up(incl, d); if (lane >= d) incl += y; }
    __shared__ int ws[8];
    if (lane == 63) ws[wid] = incl;
    __syncthreads();
    if (threadIdx.x == 0) { int a = 0; for (int w = 0; w < 8; w++) { int t = ws[w]; ws[w] = a; a += t; } }
    __syncthreads();
    int excl = incl - v + ws[wid];
    if (threadIdx.x < nb) part[threadIdx.x] = excl;
    if (threadIdx.x == nb - 1) row_off[N] = excl + v;
}

__global__ void k_scan3(const int* cnt, const int* __restrict__ part,
                        int* row_off, int* cursor, int n) {
    int i = blockIdx.x * 256 + threadIdx.x;
    int lane = threadIdx.x & 63, wid = threadIdx.x >> 6;
    int v = (i < n) ? cnt[i] : 0;
    int incl = v;
    for (int d = 1; d < 64; d <<= 1) { int y = __shfl_up(incl, d); if (lane >= d) incl += y; }
    __shared__ int ws[4];
    if (lane == 63) ws[wid] = incl;
    __syncthreads();
    if (threadIdx.x == 0) { int a = 0; for (int w = 0; w < 4; w++) { int t = ws[w]; ws[w] = a; a += t; } }
    __syncthreads();
    int excl = incl - v + ws[wid] + part[blockIdx.x];
    if (i < n) { row_off[i] = excl; cursor[i] = excl; }
}

__global__ void k_scatter(const int* __restrict__ src, const int* __restrict__ dst,
                          int* __restrict__ cursor, int* __restrict__ col, int E) {
    int e = blockIdx.x * 256 + threadIdx.x;
    if (e < E) {
        int d = dst[e];
        int p = atomicAdd(&cursor[d], 1);
        col[p] = src[e];
    }
}

// ---------------- fused column-stats epilogue ----------------
// Each lane holds a 64-col row in acc[]; reduce-scatter butterfly over 64 lanes
// -> column sums land distributed across lane pairs -> LDS -> 1 global atomic/col/block.
__device__ __forceinline__ void col_stats_butterfly(const float (&acc)[64], bool valid, int lane,
                                                    float* ldsr) {
#pragma unroll
    for (int c = 0; c < 2; c++) {
        float sv[16], qv[16];
        // first step d=32, fused with masked init + squaring
        {
            bool hi = (lane & 32) != 0;
#pragma unroll
            for (int i = 0; i < 16; i++) {
                float vlo = valid ? acc[c * 32 + i] : 0.f;
                float vhi = valid ? acc[c * 32 + 16 + i] : 0.f;
                float gs = hi ? vlo : vhi;
                float ks = hi ? vhi : vlo;
                sv[i] = ks + __shfl_xor(gs, 32);
                float qlo = vlo * vlo, qhi = vhi * vhi;
                float gq = hi ? qlo : qhi;
                float kq = hi ? qhi : qlo;
                qv[i] = kq + __shfl_xor(gq, 32);
            }
        }
#pragma unroll
        for (int d = 16; d >= 2; d >>= 1) {
            bool hi = (lane & d) != 0;
            const int half = d >> 1;
#pragma unroll
            for (int i = 0; i < 16; i++) {  // only i<half meaningful; guard below
                if (i < half) {
                    float gs = hi ? sv[i] : sv[i + half];
                    float ks = hi ? sv[i + half] : sv[i];
                    sv[i] = ks + __shfl_xor(gs, d);
                    float gq = hi ? qv[i] : qv[i + half];
                    float kq = hi ? qv[i + half] : qv[i];
                    qv[i] = kq + __shfl_xor(gq, d);
                }
            }
        }
        sv[0] += __shfl_xor(sv[0], 1);
        qv[0] += __shfl_xor(qv[0], 1);
        if ((lane & 1) == 0) {
            int colj = c * 32 + (lane >> 1);
            atomicAdd(&ldsr[colj], sv[0]);
            atomicAdd(&ldsr[64 + colj], qv[0]);
        }
    }
}

// ---------------- GEMM: C[n x NCOL] = act(A[n x 64]) @ W[64 x NCOL] + bias ----------------
// AFF: act = relu_aff with (s,t) from (rawIn,g,b) built in LDS. STATS: fuse column stats of C
// into rawOut (requires all threads alive for shuffles/barriers).
template <int NCOL, bool AFF, bool STATS>
__global__ __launch_bounds__(256) void k_gemm64(const float* __restrict__ A,
                                                const float* __restrict__ rawIn, const float* __restrict__ g,
                                                const float* __restrict__ b, float invN,
                                                const float* __restrict__ W, const float* __restrict__ bias,
                                                float* __restrict__ C, float* __restrict__ rawOut, int n) {
    __shared__ float stl[2 * HID];
    __shared__ float ldsr[128];
    if (AFF && threadIdx.x < HID) {
        float s, t;
        bn_fin(rawIn, g, b, invN, threadIdx.x, s, t);
        stl[threadIdx.x] = s;
        stl[HID + threadIdx.x] = t;
    }
    if (STATS && threadIdx.x < 128) ldsr[threadIdx.x] = 0.f;
    if (AFF || STATS) __syncthreads();

    int row = blockIdx.x * 256 + threadIdx.x;
    bool valid = row < n;
    if (!STATS && !valid) return;
    int rrow = valid ? row : 0;

    float acc[NCOL];
#pragma unroll
    for (int j = 0; j < NCOL; j++) acc[j] = bias[j];
    const float4* a4 = (const float4*)(A + (size_t)rrow * HID);
    for (int kk = 0; kk < HID / 4; kk++) {
        float4 av = a4[kk];
        float a[4] = {av.x, av.y, av.z, av.w};
#pragma unroll
        for (int u = 0; u < 4; u++) {
            int k = kk * 4 + u;
            float xv = a[u];
            if (AFF) xv = relu_aff(xv, stl[k], stl[HID + k]);
#pragma unroll
            for (int j = 0; j < NCOL; j++) acc[j] = fmaf(xv, W[k * NCOL + j], acc[j]);
        }
    }
    if (valid) {
        float* c = C + (size_t)row * NCOL;
        if constexpr (NCOL % 4 == 0) {
#pragma unroll
            for (int j = 0; j < NCOL / 4; j++)
                ((float4*)c)[j] = make_float4(acc[4 * j], acc[4 * j + 1], acc[4 * j + 2], acc[4 * j + 3]);
        } else {
#pragma unroll
            for (int j = 0; j < NCOL; j++) c[j] = acc[j];
        }
    }
    if constexpr (STATS) {
        static_assert(!STATS || NCOL == 64, "stats epilogue assumes 64 cols");
        int lane = threadIdx.x & 63;
        col_stats_butterfly(acc, valid, lane, ldsr);
        __syncthreads();
        if (threadIdx.x < 128) atomicAdd(&rawOut[threadIdx.x], ldsr[threadIdx.x]);
    }
}

// concat GEMM: C = [h0|h1|h2|h3] @ W[256 x 64] + bias, with per-part double affine
// part0: h = relu_aff(pre0; s0,t0) (second affine = identity); parts1-3: h = relu(sp*relu(s2*z+t2)+tp)
__global__ __launch_bounds__(256) void k_gemm_out1(const float* __restrict__ B0, const float* __restrict__ B1,
                                                   const float* __restrict__ B2, const float* __restrict__ B3,
                                                   const float* __restrict__ raw0,
                                                   const float* __restrict__ g_in, const float* __restrict__ be_in,
                                                   const float* __restrict__ rawS2, // 3 stages, stride 3*128
                                                   const float* __restrict__ g2, const float* __restrict__ be2,
                                                   const float* __restrict__ rawSP, // 3 stages, stride 3*128
                                                   const float* __restrict__ g_post, const float* __restrict__ be_post,
                                                   float invN,
                                                   const float* __restrict__ W, const float* __restrict__ bias,
                                                   float* __restrict__ C, float* __restrict__ rawOut, int n) {
    __shared__ float stl[4][4 * HID];  // per part: s2[64], t2[64], sp[64], tp[64]
    __shared__ float ldsr[128];
    {
        int p = threadIdx.x >> 6, c = threadIdx.x & 63;
        float s2, t2, sp, tp;
        if (p == 0) {
            bn_fin(raw0, g_in, be_in, invN, c, s2, t2);
            sp = 1.f; tp = 0.f;
        } else {
            int i = p - 1;
            bn_fin(rawS2 + (size_t)i * 3 * 128, g2 + i * HID, be2 + i * HID, invN, c, s2, t2);
            bn_fin(rawSP + (size_t)i * 3 * 128, g_post + i * HID, be_post + i * HID, invN, c, sp, tp);
        }
        stl[p][c] = s2;
        stl[p][HID + c] = t2;
        stl[p][2 * HID + c] = sp;
        stl[p][3 * HID + c] = tp;
        if (threadIdx.x < 128) ldsr[threadIdx.x] = 0.f;
        __syncthreads();
    }
    int row = blockIdx.x * 256 + threadIdx.x;
    bool valid = row < n;
    int rrow = valid ? row : 0;
    float acc[HID];
#pragma unroll
    for (int j = 0; j < HID; j++) acc[j] = bias[j];
    const float* bufs[4] = {B0, B1, B2, B3};
#pragma unroll
    for (int pp = 0; pp < 4; pp++) {
        const float4* a4 = (const float4*)(bufs[pp] + (size_t)rrow * HID);
        const float* Wp = W + pp * HID * HID;
        for (int kk = 0; kk < HID / 4; kk++) {
            float4 av = a4[kk];
            float a[4] = {av.x, av.y, av.z, av.w};
#pragma unroll
            for (int u = 0; u < 4; u++) {
                int k = kk * 4 + u;
                float xv = relu_aff(a[u], stl[pp][k], stl[pp][HID + k]);
                xv = relu_aff(xv, stl[pp][2 * HID + k], stl[pp][3 * HID + k]);
#pragma unroll
                for (int j = 0; j < HID; j++) acc[j] = fmaf(xv, Wp[k * HID + j], acc[j]);
            }
        }
    }
    if (valid) {
        float4* c4 = (float4*)(C + (size_t)row * HID);
#pragma unroll
        for (int j = 0; j < HID / 4; j++)
            c4[j] = make_float4(acc[4 * j], acc[4 * j + 1], acc[4 * j + 2], acc[4 * j + 3]);
    }
    int lane = threadIdx.x & 63;
    col_stats_butterfly(acc, valid, lane, ldsr);
    __syncthreads();
    if (threadIdx.x < 128) atomicAdd(&rawOut[threadIdx.x], ldsr[threadIdx.x]);
}

// ---------------- aggregation: o = (1+eps)*act(h) + sum act(h[src]) ----------------
// act applies one (layer 0) or two (layers 1,2) relu_aff stages per-lane from raw stats.
template <bool DBL>
__global__ __launch_bounds__(256) void k_agg(const float* __restrict__ hb,
                                             const float* __restrict__ rawA, const float* __restrict__ gA,
                                             const float* __restrict__ bA,
                                             const float* __restrict__ rawB, const float* __restrict__ gB,
                                             const float* __restrict__ bB, float invN,
                                             const int* __restrict__ row_off, const int* __restrict__ col,
                                             const float* __restrict__ epsp, int li,
                                             float* __restrict__ o, int n) {
    int wid = threadIdx.x >> 6, lane = threadIdx.x & 63;
    int node = blockIdx.x * 4 + wid;
    if (node >= n) return;
    float sA, tA, sB = 0.f, tB = 0.f;
    bn_fin(rawA, gA, bA, invN, lane, sA, tA);
    if (DBL) bn_fin(rawB, gB, bB, invN, lane, sB, tB);
#define ACT(v) (DBL ? relu_aff(relu_aff((v), sA, tA), sB, tB) : relu_aff((v), sA, tA))
    float ope = 1.f + epsp[li];
    float acc = ope * ACT(hb[(size_t)node * HID + lane]);
    int e = row_off[node], b1 = row_off[node + 1];

    while (e + 8 <= b1) {
        int i0 = col[e], i1 = col[e + 1], i2 = col[e + 2], i3 = col[e + 3];
        int i4 = col[e + 4], i5 = col[e + 5], i6 = col[e + 6], i7 = col[e + 7];
        float v0 = hb[(size_t)i0 * HID + lane], v1 = hb[(size_t)i1 * HID + lane];
        float v2 = hb[(size_t)i2 * HID + lane], v3 = hb[(size_t)i3 * HID + lane];
        float v4 = hb[(size_t)i4 * HID + lane], v5 = hb[(size_t)i5 * HID + lane];
        float v6 = hb[(size_t)i6 * HID + lane], v7 = hb[(size_t)i7 * HID + lane];
        acc += ACT(v0) + ACT(v1) + ACT(v2) + ACT(v3);
        acc += ACT(v4) + ACT(v5) + ACT(v6) + ACT(v7);
        e += 8;
    }
    if (e + 4 <= b1) {
        int i0 = col[e], i1 = col[e + 1], i2 = col[e + 2], i3 = col[e + 3];
        float v0 = hb[(size_t)i0 * HID + lane], v1 = hb[(size_t)i1 * HID + lane];
        float v2 = hb[(size_t)i2 * HID + lane], v3 = hb[(size_t)i3 * HID + lane];
        acc += ACT(v0) + ACT(v1) + ACT(v2) + ACT(v3);
        e += 4;
    }
    if (e + 2 <= b1) {
        int i0 = col[e], i1 = col[e + 1];
        float v0 = hb[(size_t)i0 * HID + lane], v1 = hb[(size_t)i1 * HID + lane];
        acc += ACT(v0) + ACT(v1);
        e += 2;
    }
    if (e < b1) acc += ACT(hb[(size_t)col[e] * HID + lane]);
#undef ACT
    o[(size_t)node * HID + lane] = acc;
}

// read-only: stats of relu_aff(X; affine from rawIn,g,b) -> rawOut
__global__ __launch_bounds__(256) void k_poststats(const float* __restrict__ X,
                                                   const float* __restrict__ rawIn,
                                                   const float* __restrict__ g, const float* __restrict__ b,
                                                   float invN,
                                                   float* __restrict__ rawOut, long long n64) {
    long long stride = (long long)gridDim.x * 256;
    long long i0 = (long long)blockIdx.x * 256 + threadIdx.x;
    int col = threadIdx.x & 63;
    float sA, tA;
    bn_fin(rawIn, g, b, invN, col, sA, tA);
    float s = 0.f, q = 0.f;
    for (long long i = i0; i < n64; i += stride) {
        float v = relu_aff(X[i], sA, tA);
        s += v; q = fmaf(v, v, q);
    }
    __shared__ float ls[256], lq[256];
    ls[threadIdx.x] = s; lq[threadIdx.x] = q;
    __syncthreads();
    if (threadIdx.x < 64) {
        s = ls[threadIdx.x] + ls[threadIdx.x + 64] + ls[threadIdx.x + 128] + ls[threadIdx.x + 192];
        q = lq[threadIdx.x] + lq[threadIdx.x + 64] + lq[threadIdx.x + 128] + lq[threadIdx.x + 192];
        atomicAdd(&rawOut[col], s);
        atomicAdd(&rawOut[64 + col], q);
    }
}

extern "C" void kernel_launch(void* const* d_in, const int* in_sizes, int n_in,
                              void* d_out, int out_size, void* d_ws, size_t ws_size,
                              hipStream_t stream) {
    const float* x = (const float*)d_in[0];
    const int* ei = (const int*)d_in[1];
    const float* W_in = (const float*)d_in[2];
    const float* b_in = (const float*)d_in[3];
    const float* g_in = (const float*)d_in[4];
    const float* be_in = (const float*)d_in[5];
    const float* epsp = (const float*)d_in[6];
    const float* W1 = (const float*)d_in[7];
    const float* b1 = (const float*)d_in[8];
    const float* g1 = (const float*)d_in[9];
    const float* be1 = (const float*)d_in[10];
    const float* W2 = (const float*)d_in[11];
    const float* b2 = (const float*)d_in[12];
    const float* g2 = (const float*)d_in[13];
    const float* be2 = (const float*)d_in[14];
    const float* g_post = (const float*)d_in[15];
    const float* be_post = (const float*)d_in[16];
    const float* W_out1 = (const float*)d_in[17];
    const float* b_out1 = (const float*)d_in[18];
    const float* g_out = (const float*)d_in[19];
    const float* be_out = (const float*)d_in[20];
    const float* W_out2 = (const float*)d_in[21];
    const float* b_out2 = (const float*)d_in[22];

    const int N = in_sizes[0] / HID;
    const int E = in_sizes[1] / 2;
    const int* srcp = ei;
    const int* dstp = ei + E;

    size_t NODE = (size_t)N * HID;
    float* f = (float*)d_ws;
    float* pre0 = f;                 // stage-0 pre-BN (kept for concat)
    float* z0 = f + NODE;            // layer i pre-BN2 z (kept for concat, affines applied on the fly)
    float* z1 = f + 2 * NODE;
    float* z2 = f + 3 * NODE;
    float* o = f + 4 * NODE;         // aggregation output
    float* p = f + 5 * NODE;         // gemm1 output / head pre-BN (reused)
    int* rc = (int*)(f + 6 * NODE);  // counts -> row offsets, N+1
    int* cursor = rc + (N + 1);
    int* col = cursor + N;           // E
    int* part = col + E;             // scan partials, <=512
    float* raw = (float*)(part + 512);  // 11 stages x {sum[64], sumsq[64]}

    size_t need = (size_t)(6 * NODE) * 4 + ((size_t)(N + 1) + N + E + 512) * 4 + (size_t)11 * 128 * 4;
    if (ws_size < need) return;  // fail loudly (output stays poisoned)

    float invN = 1.0f / (float)N;
    int nb = (N + 255) / 256;
    int gb = (N + 255) / 256;
    int eb = (E + 255) / 256;

    hipMemsetAsync(rc, 0, (size_t)(N + 1) * sizeof(int), stream);
    hipMemsetAsync(raw, 0, (size_t)11 * 128 * sizeof(float), stream);

    k_hist<<<eb, 256, 0, stream>>>(dstp, rc, E);
    k_scan1<<<nb, 256, 0, stream>>>(rc, part, N);
    k_scan2<<<1, 512, 0, stream>>>(part, nb, rc, N);
    k_scan3<<<nb, 256, 0, stream>>>(rc, part, rc, cursor, N);
    k_scatter<<<eb, 256, 0, stream>>>(srcp, dstp, cursor, col, E);

    // input projection + fused stats -> raw[0]
    k_gemm64<HID, false, true><<<gb, 256, 0, stream>>>(x, nullptr, nullptr, nullptr, invN,
                                                       W_in, b_in, pre0, raw, N);

    float* zb[3] = {z0, z1, z2};
    for (int i = 0; i < LAYERS; i++) {
        int s1 = 1 + 3 * i, s2 = 2 + 3 * i, sp = 3 + 3 * i;
        const float* hb = (i == 0) ? pre0 : zb[i - 1];
        if (i == 0) {
            k_agg<false><<<(N + 3) / 4, 256, 0, stream>>>(hb, raw, g_in, be_in,
                                                          nullptr, nullptr, nullptr, invN,
                                                          rc, col, epsp, i, o, N);
        } else {
            int ps2 = 2 + 3 * (i - 1), psp = 3 + 3 * (i - 1);
            k_agg<true><<<(N + 3) / 4, 256, 0, stream>>>(hb,
                                                         raw + (size_t)ps2 * 128, g2 + (i - 1) * HID, be2 + (i - 1) * HID,
                                                         raw + (size_t)psp * 128, g_post + (i - 1) * HID, be_post + (i - 1) * HID,
                                                         invN, rc, col, epsp, i, o, N);
        }
        k_gemm64<HID, false, true><<<gb, 256, 0, stream>>>(o, nullptr, nullptr, nullptr, invN,
                                                           W1 + (size_t)i * HID * HID, b1 + i * HID,
                                                           p, raw + (size_t)s1 * 128, N);
        k_gemm64<HID, true, true><<<gb, 256, 0, stream>>>(p, raw + (size_t)s1 * 128, g1 + i * HID, be1 + i * HID, invN,
                                                          W2 + (size_t)i * HID * HID, b2 + i * HID,
                                                          zb[i], raw + (size_t)s2 * 128, N);
        k_poststats<<<512, 256, 0, stream>>>(zb[i], raw + (size_t)s2 * 128, g2 + i * HID, be2 + i * HID, invN,
                                             raw + (size_t)sp * 128, (long long)NODE);
    }

    // head: concat (double affines on the fly) -> 256x64 GEMM + stats -> 64x10 GEMM
    k_gemm_out1<<<gb, 256, 0, stream>>>(pre0, z0, z1, z2,
                                        raw, g_in, be_in,
                                        raw + 2 * 128, g2, be2,
                                        raw + 3 * 128, g_post, be_post,
                                        invN, W_out1, b_out1, p, raw + 10 * 128, N);
    k_gemm64<10, true, false><<<gb, 256, 0, stream>>>(p, raw + 10 * 128, g_out, be_out, invN,
                                                      W_out2, b_out2, (float*)d_out, nullptr, N);
}

// Round 4
// 1240.477 us; speedup vs baseline: 1.0136x; 1.0136x over previous
//
#include <hip/hip_runtime.h>

// GIN forward, MI355X. Round 4:
//  - FIX: __launch_bounds__(256, 2) on all GEMM kernels. Compiler default waves/EU
//    heuristic capped VGPRs at 36-68 and spilled acc[64] to scratch since round 1
//    (evidence: r3 k_gemm_out1 VGPR_Count=68 with 64 accumulators, WRITE_SIZE 39MB vs
//    25.7MB ideal, VALUBusy 20%). Cap 256 VGPR/wave keeps acc in registers.
//  - otherwise identical to round 3 (fused stats epilogues, double-affine on the fly)

#define HID 64
#define LAYERS 3
#define BN_EPS 1e-5f

__device__ __forceinline__ float relu_aff(float x, float s, float t) {
    return fmaxf(fmaf(x, s, t), 0.f);
}

// compute affine (s,t) for column c from raw sums
__device__ __forceinline__ void bn_fin(const float* __restrict__ raw, const float* __restrict__ g,
                                       const float* __restrict__ b, float invN, int c,
                                       float& s, float& t) {
    float m = raw[c] * invN;
    float v = fmaf(-m, m, raw[64 + c] * invN);
    float r = rsqrtf(v + BN_EPS);
    s = r * g[c];
    t = fmaf(-m, s, b[c]);
}

// ---------------- CSR build ----------------
__global__ void k_hist(const int* __restrict__ dst, int* __restrict__ cnt, int E) {
    int e = blockIdx.x * 256 + threadIdx.x;
    if (e < E) atomicAdd(&cnt[dst[e]], 1);
}

__global__ void k_scan1(const int* __restrict__ cnt, int* __restrict__ part, int n) {
    __shared__ int sm[256];
    int i = blockIdx.x * 256 + threadIdx.x;
    sm[threadIdx.x] = (i < n) ? cnt[i] : 0;
    __syncthreads();
    for (int s = 128; s > 0; s >>= 1) {
        if (threadIdx.x < s) sm[threadIdx.x] += sm[threadIdx.x + s];
        __syncthreads();
    }
    if (threadIdx.x == 0) part[blockIdx.x] = sm[0];
}

__global__ void k_scan2(int* part, int nb, int* row_off, int N) {
    int lane = threadIdx.x & 63, wid = threadIdx.x >> 6;
    int v = (threadIdx.x < nb) ? part[threadIdx.x] : 0;
    int incl = v;
    for (int d = 1; d < 64; d <<= 1) { int y = __shfl_up(incl, d); if (lane >= d) incl += y; }
    __shared__ int ws[8];
    if (lane == 63) ws[wid] = incl;
    __syncthreads();
    if (threadIdx.x == 0) { int a = 0; for (int w = 0; w < 8; w++) { int t = ws[w]; ws[w] = a; a += t; } }
    __syncthreads();
    int excl = incl - v + ws[wid];
    if (threadIdx.x < nb) part[threadIdx.x] = excl;
    if (threadIdx.x == nb - 1) row_off[N] = excl + v;
}

__global__ void k_scan3(const int* cnt, const int* __restrict__ part,
                        int* row_off, int* cursor, int n) {
    int i = blockIdx.x * 256 + threadIdx.x;
    int lane = threadIdx.x & 63, wid = threadIdx.x >> 6;
    int v = (i < n) ? cnt[i] : 0;
    int incl = v;
    for (int d = 1; d < 64; d <<= 1) { int y = __shfl_up(incl, d); if (lane >= d) incl += y; }
    __shared__ int ws[4];
    if (lane == 63) ws[wid] = incl;
    __syncthreads();
    if (threadIdx.x == 0) { int a = 0; for (int w = 0; w < 4; w++) { int t = ws[w]; ws[w] = a; a += t; } }
    __syncthreads();
    int excl = incl - v + ws[wid] + part[blockIdx.x];
    if (i < n) { row_off[i] = excl; cursor[i] = excl; }
}

__global__ void k_scatter(const int* __restrict__ src, const int* __restrict__ dst,
                          int* __restrict__ cursor, int* __restrict__ col, int E) {
    int e = blockIdx.x * 256 + threadIdx.x;
    if (e < E) {
        int d = dst[e];
        int p = atomicAdd(&cursor[d], 1);
        col[p] = src[e];
    }
}

// ---------------- fused column-stats epilogue ----------------
// Each lane holds a 64-col row in acc[]; reduce-scatter butterfly over 64 lanes
// -> column sums land distributed across lane pairs -> LDS -> 1 global atomic/col/block.
__device__ __forceinline__ void col_stats_butterfly(const float (&acc)[64], bool valid, int lane,
                                                    float* ldsr) {
#pragma unroll
    for (int c = 0; c < 2; c++) {
        float sv[16], qv[16];
        // first step d=32, fused with masked init + squaring
        {
            bool hi = (lane & 32) != 0;
#pragma unroll
            for (int i = 0; i < 16; i++) {
                float vlo = valid ? acc[c * 32 + i] : 0.f;
                float vhi = valid ? acc[c * 32 + 16 + i] : 0.f;
                float gs = hi ? vlo : vhi;
                float ks = hi ? vhi : vlo;
                sv[i] = ks + __shfl_xor(gs, 32);
                float qlo = vlo * vlo, qhi = vhi * vhi;
                float gq = hi ? qlo : qhi;
                float kq = hi ? qhi : qlo;
                qv[i] = kq + __shfl_xor(gq, 32);
            }
        }
#pragma unroll
        for (int d = 16; d >= 2; d >>= 1) {
            bool hi = (lane & d) != 0;
            const int half = d >> 1;
#pragma unroll
            for (int i = 0; i < 16; i++) {
                if (i < half) {
                    float gs = hi ? sv[i] : sv[i + half];
                    float ks = hi ? sv[i + half] : sv[i];
                    sv[i] = ks + __shfl_xor(gs, d);
                    float gq = hi ? qv[i] : qv[i + half];
                    float kq = hi ? qv[i + half] : qv[i];
                    qv[i] = kq + __shfl_xor(gq, d);
                }
            }
        }
        sv[0] += __shfl_xor(sv[0], 1);
        qv[0] += __shfl_xor(qv[0], 1);
        if ((lane & 1) == 0) {
            int colj = c * 32 + (lane >> 1);
            atomicAdd(&ldsr[colj], sv[0]);
            atomicAdd(&ldsr[64 + colj], qv[0]);
        }
    }
}

// ---------------- GEMM: C[n x NCOL] = act(A[n x 64]) @ W[64 x NCOL] + bias ----------------
// AFF: act = relu_aff with (s,t) from (rawIn,g,b) built in LDS. STATS: fuse column stats of C
// into rawOut. __launch_bounds__(256,2): VGPR cap 256 so acc[64] stays in registers.
template <int NCOL, bool AFF, bool STATS>
__global__ __launch_bounds__(256, 2) void k_gemm64(const float* __restrict__ A,
                                                   const float* __restrict__ rawIn, const float* __restrict__ g,
                                                   const float* __restrict__ b, float invN,
                                                   const float* __restrict__ W, const float* __restrict__ bias,
                                                   float* __restrict__ C, float* __restrict__ rawOut, int n) {
    __shared__ float stl[2 * HID];
    __shared__ float ldsr[128];
    if (AFF && threadIdx.x < HID) {
        float s, t;
        bn_fin(rawIn, g, b, invN, threadIdx.x, s, t);
        stl[threadIdx.x] = s;
        stl[HID + threadIdx.x] = t;
    }
    if (STATS && threadIdx.x < 128) ldsr[threadIdx.x] = 0.f;
    if (AFF || STATS) __syncthreads();

    int row = blockIdx.x * 256 + threadIdx.x;
    bool valid = row < n;
    if (!STATS && !valid) return;
    int rrow = valid ? row : 0;

    float acc[NCOL];
#pragma unroll
    for (int j = 0; j < NCOL; j++) acc[j] = bias[j];
    const float4* a4 = (const float4*)(A + (size_t)rrow * HID);
    for (int kk = 0; kk < HID / 4; kk++) {
        float4 av = a4[kk];
        float a[4] = {av.x, av.y, av.z, av.w};
#pragma unroll
        for (int u = 0; u < 4; u++) {
            int k = kk * 4 + u;
            float xv = a[u];
            if (AFF) xv = relu_aff(xv, stl[k], stl[HID + k]);
#pragma unroll
            for (int j = 0; j < NCOL; j++) acc[j] = fmaf(xv, W[k * NCOL + j], acc[j]);
        }
    }
    if (valid) {
        float* c = C + (size_t)row * NCOL;
        if constexpr (NCOL % 4 == 0) {
#pragma unroll
            for (int j = 0; j < NCOL / 4; j++)
                ((float4*)c)[j] = make_float4(acc[4 * j], acc[4 * j + 1], acc[4 * j + 2], acc[4 * j + 3]);
        } else {
#pragma unroll
            for (int j = 0; j < NCOL; j++) c[j] = acc[j];
        }
    }
    if constexpr (STATS) {
        static_assert(!STATS || NCOL == 64, "stats epilogue assumes 64 cols");
        int lane = threadIdx.x & 63;
        col_stats_butterfly(acc, valid, lane, ldsr);
        __syncthreads();
        if (threadIdx.x < 128) atomicAdd(&rawOut[threadIdx.x], ldsr[threadIdx.x]);
    }
}

// concat GEMM: C = [h0|h1|h2|h3] @ W[256 x 64] + bias, with per-part double affine
__global__ __launch_bounds__(256, 2) void k_gemm_out1(const float* __restrict__ B0, const float* __restrict__ B1,
                                                      const float* __restrict__ B2, const float* __restrict__ B3,
                                                      const float* __restrict__ raw0,
                                                      const float* __restrict__ g_in, const float* __restrict__ be_in,
                                                      const float* __restrict__ rawS2,
                                                      const float* __restrict__ g2, const float* __restrict__ be2,
                                                      const float* __restrict__ rawSP,
                                                      const float* __restrict__ g_post, const float* __restrict__ be_post,
                                                      float invN,
                                                      const float* __restrict__ W, const float* __restrict__ bias,
                                                      float* __restrict__ C, float* __restrict__ rawOut, int n) {
    __shared__ float stl[4][4 * HID];  // per part: s2[64], t2[64], sp[64], tp[64]
    __shared__ float ldsr[128];
    {
        int p = threadIdx.x >> 6, c = threadIdx.x & 63;
        float s2, t2, sp, tp;
        if (p == 0) {
            bn_fin(raw0, g_in, be_in, invN, c, s2, t2);
            sp = 1.f; tp = 0.f;
        } else {
            int i = p - 1;
            bn_fin(rawS2 + (size_t)i * 3 * 128, g2 + i * HID, be2 + i * HID, invN, c, s2, t2);
            bn_fin(rawSP + (size_t)i * 3 * 128, g_post + i * HID, be_post + i * HID, invN, c, sp, tp);
        }
        stl[p][c] = s2;
        stl[p][HID + c] = t2;
        stl[p][2 * HID + c] = sp;
        stl[p][3 * HID + c] = tp;
        if (threadIdx.x < 128) ldsr[threadIdx.x] = 0.f;
        __syncthreads();
    }
    int row = blockIdx.x * 256 + threadIdx.x;
    bool valid = row < n;
    int rrow = valid ? row : 0;
    float acc[HID];
#pragma unroll
    for (int j = 0; j < HID; j++) acc[j] = bias[j];
    const float* bufs[4] = {B0, B1, B2, B3};
#pragma unroll
    for (int pp = 0; pp < 4; pp++) {
        const float4* a4 = (const float4*)(bufs[pp] + (size_t)rrow * HID);
        const float* Wp = W + pp * HID * HID;
        for (int kk = 0; kk < HID / 4; kk++) {
            float4 av = a4[kk];
            float a[4] = {av.x, av.y, av.z, av.w};
#pragma unroll
            for (int u = 0; u < 4; u++) {
                int k = kk * 4 + u;
                float xv = relu_aff(a[u], stl[pp][k], stl[pp][HID + k]);
                xv = relu_aff(xv, stl[pp][2 * HID + k], stl[pp][3 * HID + k]);
#pragma unroll
                for (int j = 0; j < HID; j++) acc[j] = fmaf(xv, Wp[k * HID + j], acc[j]);
            }
        }
    }
    if (valid) {
        float4* c4 = (float4*)(C + (size_t)row * HID);
#pragma unroll
        for (int j = 0; j < HID / 4; j++)
            c4[j] = make_float4(acc[4 * j], acc[4 * j + 1], acc[4 * j + 2], acc[4 * j + 3]);
    }
    int lane = threadIdx.x & 63;
    col_stats_butterfly(acc, valid, lane, ldsr);
    __syncthreads();
    if (threadIdx.x < 128) atomicAdd(&rawOut[threadIdx.x], ldsr[threadIdx.x]);
}

// ---------------- aggregation: o = (1+eps)*act(h) + sum act(h[src]) ----------------
template <bool DBL>
__global__ __launch_bounds__(256) void k_agg(const float* __restrict__ hb,
                                             const float* __restrict__ rawA, const float* __restrict__ gA,
                                             const float* __restrict__ bA,
                                             const float* __restrict__ rawB, const float* __restrict__ gB,
                                             const float* __restrict__ bB, float invN,
                                             const int* __restrict__ row_off, const int* __restrict__ col,
                                             const float* __restrict__ epsp, int li,
                                             float* __restrict__ o, int n) {
    int wid = threadIdx.x >> 6, lane = threadIdx.x & 63;
    int node = blockIdx.x * 4 + wid;
    if (node >= n) return;
    float sA, tA, sB = 0.f, tB = 0.f;
    bn_fin(rawA, gA, bA, invN, lane, sA, tA);
    if (DBL) bn_fin(rawB, gB, bB, invN, lane, sB, tB);
#define ACT(v) (DBL ? relu_aff(relu_aff((v), sA, tA), sB, tB) : relu_aff((v), sA, tA))
    float ope = 1.f + epsp[li];
    float acc = ope * ACT(hb[(size_t)node * HID + lane]);
    int e = row_off[node], b1 = row_off[node + 1];

    while (e + 8 <= b1) {
        int i0 = col[e], i1 = col[e + 1], i2 = col[e + 2], i3 = col[e + 3];
        int i4 = col[e + 4], i5 = col[e + 5], i6 = col[e + 6], i7 = col[e + 7];
        float v0 = hb[(size_t)i0 * HID + lane], v1 = hb[(size_t)i1 * HID + lane];
        float v2 = hb[(size_t)i2 * HID + lane], v3 = hb[(size_t)i3 * HID + lane];
        float v4 = hb[(size_t)i4 * HID + lane], v5 = hb[(size_t)i5 * HID + lane];
        float v6 = hb[(size_t)i6 * HID + lane], v7 = hb[(size_t)i7 * HID + lane];
        acc += ACT(v0) + ACT(v1) + ACT(v2) + ACT(v3);
        acc += ACT(v4) + ACT(v5) + ACT(v6) + ACT(v7);
        e += 8;
    }
    if (e + 4 <= b1) {
        int i0 = col[e], i1 = col[e + 1], i2 = col[e + 2], i3 = col[e + 3];
        float v0 = hb[(size_t)i0 * HID + lane], v1 = hb[(size_t)i1 * HID + lane];
        float v2 = hb[(size_t)i2 * HID + lane], v3 = hb[(size_t)i3 * HID + lane];
        acc += ACT(v0) + ACT(v1) + ACT(v2) + ACT(v3);
        e += 4;
    }
    if (e + 2 <= b1) {
        int i0 = col[e], i1 = col[e + 1];
        float v0 = hb[(size_t)i0 * HID + lane], v1 = hb[(size_t)i1 * HID + lane];
        acc += ACT(v0) + ACT(v1);
        e += 2;
    }
    if (e < b1) acc += ACT(hb[(size_t)col[e] * HID + lane]);
#undef ACT
    o[(size_t)node * HID + lane] = acc;
}

// read-only: stats of relu_aff(X; affine from rawIn,g,b) -> rawOut
__global__ __launch_bounds__(256) void k_poststats(const float* __restrict__ X,
                                                   const float* __restrict__ rawIn,
                                                   const float* __restrict__ g, const float* __restrict__ b,
                                                   float invN,
                                                   float* __restrict__ rawOut, long long n64) {
    long long stride = (long long)gridDim.x * 256;
    long long i0 = (long long)blockIdx.x * 256 + threadIdx.x;
    int col = threadIdx.x & 63;
    float sA, tA;
    bn_fin(rawIn, g, b, invN, col, sA, tA);
    float s = 0.f, q = 0.f;
    for (long long i = i0; i < n64; i += stride) {
        float v = relu_aff(X[i], sA, tA);
        s += v; q = fmaf(v, v, q);
    }
    __shared__ float ls[256], lq[256];
    ls[threadIdx.x] = s; lq[threadIdx.x] = q;
    __syncthreads();
    if (threadIdx.x < 64) {
        s = ls[threadIdx.x] + ls[threadIdx.x + 64] + ls[threadIdx.x + 128] + ls[threadIdx.x + 192];
        q = lq[threadIdx.x] + lq[threadIdx.x + 64] + lq[threadIdx.x + 128] + lq[threadIdx.x + 192];
        atomicAdd(&rawOut[col], s);
        atomicAdd(&rawOut[64 + col], q);
    }
}

extern "C" void kernel_launch(void* const* d_in, const int* in_sizes, int n_in,
                              void* d_out, int out_size, void* d_ws, size_t ws_size,
                              hipStream_t stream) {
    const float* x = (const float*)d_in[0];
    const int* ei = (const int*)d_in[1];
    const float* W_in = (const float*)d_in[2];
    const float* b_in = (const float*)d_in[3];
    const float* g_in = (const float*)d_in[4];
    const float* be_in = (const float*)d_in[5];
    const float* epsp = (const float*)d_in[6];
    const float* W1 = (const float*)d_in[7];
    const float* b1 = (const float*)d_in[8];
    const float* g1 = (const float*)d_in[9];
    const float* be1 = (const float*)d_in[10];
    const float* W2 = (const float*)d_in[11];
    const float* b2 = (const float*)d_in[12];
    const float* g2 = (const float*)d_in[13];
    const float* be2 = (const float*)d_in[14];
    const float* g_post = (const float*)d_in[15];
    const float* be_post = (const float*)d_in[16];
    const float* W_out1 = (const float*)d_in[17];
    const float* b_out1 = (const float*)d_in[18];
    const float* g_out = (const float*)d_in[19];
    const float* be_out = (const float*)d_in[20];
    const float* W_out2 = (const float*)d_in[21];
    const float* b_out2 = (const float*)d_in[22];

    const int N = in_sizes[0] / HID;
    const int E = in_sizes[1] / 2;
    const int* srcp = ei;
    const int* dstp = ei + E;

    size_t NODE = (size_t)N * HID;
    float* f = (float*)d_ws;
    float* pre0 = f;                 // stage-0 pre-BN (kept for concat)
    float* z0 = f + NODE;            // layer i pre-BN2 z (kept for concat, affines applied on the fly)
    float* z1 = f + 2 * NODE;
    float* z2 = f + 3 * NODE;
    float* o = f + 4 * NODE;         // aggregation output
    float* p = f + 5 * NODE;         // gemm1 output / head pre-BN (reused)
    int* rc = (int*)(f + 6 * NODE);  // counts -> row offsets, N+1
    int* cursor = rc + (N + 1);
    int* col = cursor + N;           // E
    int* part = col + E;             // scan partials, <=512
    float* raw = (float*)(part + 512);  // 11 stages x {sum[64], sumsq[64]}

    size_t need = (size_t)(6 * NODE) * 4 + ((size_t)(N + 1) + N + E + 512) * 4 + (size_t)11 * 128 * 4;
    if (ws_size < need) return;  // fail loudly (output stays poisoned)

    float invN = 1.0f / (float)N;
    int nb = (N + 255) / 256;
    int gb = (N + 255) / 256;
    int eb = (E + 255) / 256;

    hipMemsetAsync(rc, 0, (size_t)(N + 1) * sizeof(int), stream);
    hipMemsetAsync(raw, 0, (size_t)11 * 128 * sizeof(float), stream);

    k_hist<<<eb, 256, 0, stream>>>(dstp, rc, E);
    k_scan1<<<nb, 256, 0, stream>>>(rc, part, N);
    k_scan2<<<1, 512, 0, stream>>>(part, nb, rc, N);
    k_scan3<<<nb, 256, 0, stream>>>(rc, part, rc, cursor, N);
    k_scatter<<<eb, 256, 0, stream>>>(srcp, dstp, cursor, col, E);

    // input projection + fused stats -> raw[0]
    k_gemm64<HID, false, true><<<gb, 256, 0, stream>>>(x, nullptr, nullptr, nullptr, invN,
                                                       W_in, b_in, pre0, raw, N);

    float* zb[3] = {z0, z1, z2};
    for (int i = 0; i < LAYERS; i++) {
        int s1 = 1 + 3 * i, s2 = 2 + 3 * i, sp = 3 + 3 * i;
        const float* hb = (i == 0) ? pre0 : zb[i - 1];
        if (i == 0) {
            k_agg<false><<<(N + 3) / 4, 256, 0, stream>>>(hb, raw, g_in, be_in,
                                                          nullptr, nullptr, nullptr, invN,
                                                          rc, col, epsp, i, o, N);
        } else {
            int ps2 = 2 + 3 * (i - 1), psp = 3 + 3 * (i - 1);
            k_agg<true><<<(N + 3) / 4, 256, 0, stream>>>(hb,
                                                         raw + (size_t)ps2 * 128, g2 + (i - 1) * HID, be2 + (i - 1) * HID,
                                                         raw + (size_t)psp * 128, g_post + (i - 1) * HID, be_post + (i - 1) * HID,
                                                         invN, rc, col, epsp, i, o, N);
        }
        k_gemm64<HID, false, true><<<gb, 256, 0, stream>>>(o, nullptr, nullptr, nullptr, invN,
                                                           W1 + (size_t)i * HID * HID, b1 + i * HID,
                                                           p, raw + (size_t)s1 * 128, N);
        k_gemm64<HID, true, true><<<gb, 256, 0, stream>>>(p, raw + (size_t)s1 * 128, g1 + i * HID, be1 + i * HID, invN,
                                                          W2 + (size_t)i * HID * HID, b2 + i * HID,
                                                          zb[i], raw + (size_t)s2 * 128, N);
        k_poststats<<<512, 256, 0, stream>>>(zb[i], raw + (size_t)s2 * 128, g2 + i * HID, be2 + i * HID, invN,
                                             raw + (size_t)sp * 128, (long long)NODE);
    }

    // head: concat (double affines on the fly) -> 256x64 GEMM + stats -> 64x10 GEMM
    k_gemm_out1<<<gb, 256, 0, stream>>>(pre0, z0, z1, z2,
                                        raw, g_in, be_in,
                                        raw + 2 * 128, g2, be2,
                                        raw + 3 * 128, g_post, be_post,
                                        invN, W_out1, b_out1, p, raw + 10 * 128, N);
    k_gemm64<10, true, false><<<gb, 256, 0, stream>>>(p, raw + 10 * 128, g_out, be_out, invN,
                                                      W_out2, b_out2, (float*)d_out, nullptr, N);
}

// Round 5
// 1238.279 us; speedup vs baseline: 1.0154x; 1.0018x over previous
//
#include <hip/hip_runtime.h>

// GIN forward, MI355X. Round 5:
//  - STRUCTURAL spill fix: 64-col GEMMs split into 2 column-halves (gridDim.y=2),
//    acc[32]/thread -> fits 64-VGPR occupancy quantum, no scratch spill.
//    (r3/r4 evidence: VGPR_Count=68 with acc[64] regardless of __launch_bounds__;
//    the allocator schedules for high occupancy and spills instead of using budget.)
//  - stats butterfly per half (32 cols over 64 lanes), same verified reduction order
//  - rest identical to round 3/4

#define HID 64
#define LAYERS 3
#define BN_EPS 1e-5f

__device__ __forceinline__ float relu_aff(float x, float s, float t) {
    return fmaxf(fmaf(x, s, t), 0.f);
}

__device__ __forceinline__ void bn_fin(const float* __restrict__ raw, const float* __restrict__ g,
                                       const float* __restrict__ b, float invN, int c,
                                       float& s, float& t) {
    float m = raw[c] * invN;
    float v = fmaf(-m, m, raw[64 + c] * invN);
    float r = rsqrtf(v + BN_EPS);
    s = r * g[c];
    t = fmaf(-m, s, b[c]);
}

// ---------------- CSR build ----------------
__global__ void k_hist(const int* __restrict__ dst, int* __restrict__ cnt, int E) {
    int e = blockIdx.x * 256 + threadIdx.x;
    if (e < E) atomicAdd(&cnt[dst[e]], 1);
}

__global__ void k_scan1(const int* __restrict__ cnt, int* __restrict__ part, int n) {
    __shared__ int sm[256];
    int i = blockIdx.x * 256 + threadIdx.x;
    sm[threadIdx.x] = (i < n) ? cnt[i] : 0;
    __syncthreads();
    for (int s = 128; s > 0; s >>= 1) {
        if (threadIdx.x < s) sm[threadIdx.x] += sm[threadIdx.x + s];
        __syncthreads();
    }
    if (threadIdx.x == 0) part[blockIdx.x] = sm[0];
}

__global__ void k_scan2(int* part, int nb, int* row_off, int N) {
    int lane = threadIdx.x & 63, wid = threadIdx.x >> 6;
    int v = (threadIdx.x < nb) ? part[threadIdx.x] : 0;
    int incl = v;
    for (int d = 1; d < 64; d <<= 1) { int y = __shfl_up(incl, d); if (lane >= d) incl += y; }
    __shared__ int ws[8];
    if (lane == 63) ws[wid] = incl;
    __syncthreads();
    if (threadIdx.x == 0) { int a = 0; for (int w = 0; w < 8; w++) { int t = ws[w]; ws[w] = a; a += t; } }
    __syncthreads();
    int excl = incl - v + ws[wid];
    if (threadIdx.x < nb) part[threadIdx.x] = excl;
    if (threadIdx.x == nb - 1) row_off[N] = excl + v;
}

__global__ void k_scan3(const int* cnt, const int* __restrict__ part,
                        int* row_off, int* cursor, int n) {
    int i = blockIdx.x * 256 + threadIdx.x;
    int lane = threadIdx.x & 63, wid = threadIdx.x >> 6;
    int v = (i < n) ? cnt[i] : 0;
    int incl = v;
    for (int d = 1; d < 64; d <<= 1) { int y = __shfl_up(incl, d); if (lane >= d) incl += y; }
    __shared__ int ws[4];
    if (lane == 63) ws[wid] = incl;
    __syncthreads();
    if (threadIdx.x == 0) { int a = 0; for (int w = 0; w < 4; w++) { int t = ws[w]; ws[w] = a; a += t; } }
    __syncthreads();
    int excl = incl - v + ws[wid] + part[blockIdx.x];
    if (i < n) { row_off[i] = excl; cursor[i] = excl; }
}

__global__ void k_scatter(const int* __restrict__ src, const int* __restrict__ dst,
                          int* __restrict__ cursor, int* __restrict__ col, int E) {
    int e = blockIdx.x * 256 + threadIdx.x;
    if (e < E) {
        int d = dst[e];
        int p = atomicAdd(&cursor[d], 1);
        col[p] = src[e];
    }
}

// ---------------- stats butterfly: 32 cols over 64 lanes ----------------
// After reduction, even lanes hold col (lane>>1) of this block's 32-col slice.
// ldsr layout: [0..32) sums, [32..64) sumsqs.
__device__ __forceinline__ void col_stats_butterfly32(const float (&acc)[32], bool valid, int lane,
                                                      float* ldsr) {
    float sv[16], qv[16];
    {
        bool hi = (lane & 32) != 0;
#pragma unroll
        for (int i = 0; i < 16; i++) {
            float vlo = valid ? acc[i] : 0.f;
            float vhi = valid ? acc[16 + i] : 0.f;
            float gs = hi ? vlo : vhi;
            float ks = hi ? vhi : vlo;
            sv[i] = ks + __shfl_xor(gs, 32);
            float qlo = vlo * vlo, qhi = vhi * vhi;
            float gq = hi ? qlo : qhi;
            float kq = hi ? qhi : qlo;
            qv[i] = kq + __shfl_xor(gq, 32);
        }
    }
#pragma unroll
    for (int d = 16; d >= 2; d >>= 1) {
        bool hi = (lane & d) != 0;
        const int half = d >> 1;
#pragma unroll
        for (int i = 0; i < 16; i++) {
            if (i < half) {
                float gs = hi ? sv[i] : sv[i + half];
                float ks = hi ? sv[i + half] : sv[i];
                sv[i] = ks + __shfl_xor(gs, d);
                float gq = hi ? qv[i] : qv[i + half];
                float kq = hi ? qv[i + half] : qv[i];
                qv[i] = kq + __shfl_xor(gq, d);
            }
        }
    }
    sv[0] += __shfl_xor(sv[0], 1);
    qv[0] += __shfl_xor(qv[0], 1);
    if ((lane & 1) == 0) {
        int colj = lane >> 1;
        atomicAdd(&ldsr[colj], sv[0]);
        atomicAdd(&ldsr[32 + colj], qv[0]);
    }
}

// ---------------- halved GEMM: C[:, half*32:(half+1)*32] = act(A[n x 64]) @ W[64 x 64] ----
// gridDim.y = 2 (column half). acc[32]/thread -> <=64 VGPR, no spill.
template <bool AFF, bool STATS>
__global__ __launch_bounds__(256) void k_gemm64h(const float* __restrict__ A,
                                                 const float* __restrict__ rawIn, const float* __restrict__ g,
                                                 const float* __restrict__ b, float invN,
                                                 const float* __restrict__ W, const float* __restrict__ bias,
                                                 float* __restrict__ C, float* __restrict__ rawOut, int n) {
    __shared__ float stl[2 * HID];
    __shared__ float ldsr[64];
    const int half = blockIdx.y;
    if (AFF && threadIdx.x < HID) {
        float s, t;
        bn_fin(rawIn, g, b, invN, threadIdx.x, s, t);
        stl[threadIdx.x] = s;
        stl[HID + threadIdx.x] = t;
    }
    if (STATS && threadIdx.x < 64) ldsr[threadIdx.x] = 0.f;
    if (AFF || STATS) __syncthreads();

    int row = blockIdx.x * 256 + threadIdx.x;
    bool valid = row < n;
    if (!STATS && !valid) return;
    int rrow = valid ? row : 0;

    float acc[32];
#pragma unroll
    for (int j = 0; j < 32; j++) acc[j] = bias[half * 32 + j];
    const float4* a4 = (const float4*)(A + (size_t)rrow * HID);
    const float* Wh = W + half * 32;
    for (int kk = 0; kk < HID / 4; kk++) {
        float4 av = a4[kk];
        float a[4] = {av.x, av.y, av.z, av.w};
#pragma unroll
        for (int u = 0; u < 4; u++) {
            int k = kk * 4 + u;
            float xv = a[u];
            if (AFF) xv = relu_aff(xv, stl[k], stl[HID + k]);
#pragma unroll
            for (int j = 0; j < 32; j++) acc[j] = fmaf(xv, Wh[k * HID + j], acc[j]);
        }
    }
    if (valid) {
        float4* c4 = (float4*)(C + (size_t)row * HID + half * 32);
#pragma unroll
        for (int j = 0; j < 8; j++)
            c4[j] = make_float4(acc[4 * j], acc[4 * j + 1], acc[4 * j + 2], acc[4 * j + 3]);
    }
    if constexpr (STATS) {
        int lane = threadIdx.x & 63;
        col_stats_butterfly32(acc, valid, lane, ldsr);
        __syncthreads();
        if (threadIdx.x < 64) {
            int c = threadIdx.x & 31;
            float v = ldsr[threadIdx.x];
            if (threadIdx.x < 32) atomicAdd(&rawOut[half * 32 + c], v);
            else                  atomicAdd(&rawOut[64 + half * 32 + c], v);
        }
    }
}

// concat GEMM, halved: C[:, half*32:...] = [h0|h1|h2|h3] @ W[256 x 64], double affine per part
__global__ __launch_bounds__(256) void k_gemm_out1(const float* __restrict__ B0, const float* __restrict__ B1,
                                                   const float* __restrict__ B2, const float* __restrict__ B3,
                                                   const float* __restrict__ raw0,
                                                   const float* __restrict__ g_in, const float* __restrict__ be_in,
                                                   const float* __restrict__ rawS2,
                                                   const float* __restrict__ g2, const float* __restrict__ be2,
                                                   const float* __restrict__ rawSP,
                                                   const float* __restrict__ g_post, const float* __restrict__ be_post,
                                                   float invN,
                                                   const float* __restrict__ W, const float* __restrict__ bias,
                                                   float* __restrict__ C, float* __restrict__ rawOut, int n) {
    __shared__ float stl[4][4 * HID];  // per part: s2[64], t2[64], sp[64], tp[64]
    __shared__ float ldsr[64];
    const int half = blockIdx.y;
    {
        int p = threadIdx.x >> 6, c = threadIdx.x & 63;
        float s2, t2, sp, tp;
        if (p == 0) {
            bn_fin(raw0, g_in, be_in, invN, c, s2, t2);
            sp = 1.f; tp = 0.f;
        } else {
            int i = p - 1;
            bn_fin(rawS2 + (size_t)i * 3 * 128, g2 + i * HID, be2 + i * HID, invN, c, s2, t2);
            bn_fin(rawSP + (size_t)i * 3 * 128, g_post + i * HID, be_post + i * HID, invN, c, sp, tp);
        }
        stl[p][c] = s2;
        stl[p][HID + c] = t2;
        stl[p][2 * HID + c] = sp;
        stl[p][3 * HID + c] = tp;
        if (threadIdx.x < 64) ldsr[threadIdx.x] = 0.f;
        __syncthreads();
    }
    int row = blockIdx.x * 256 + threadIdx.x;
    bool valid = row < n;
    int rrow = valid ? row : 0;
    float acc[32];
#pragma unroll
    for (int j = 0; j < 32; j++) acc[j] = bias[half * 32 + j];
    const float* bufs[4] = {B0, B1, B2, B3};
#pragma unroll
    for (int pp = 0; pp < 4; pp++) {
        const float4* a4 = (const float4*)(bufs[pp] + (size_t)rrow * HID);
        const float* Wp = W + pp * HID * HID + half * 32;
        for (int kk = 0; kk < HID / 4; kk++) {
            float4 av = a4[kk];
            float a[4] = {av.x, av.y, av.z, av.w};
#pragma unroll
            for (int u = 0; u < 4; u++) {
                int k = kk * 4 + u;
                float xv = relu_aff(a[u], stl[pp][k], stl[pp][HID + k]);
                xv = relu_aff(xv, stl[pp][2 * HID + k], stl[pp][3 * HID + k]);
#pragma unroll
                for (int j = 0; j < 32; j++) acc[j] = fmaf(xv, Wp[k * HID + j], acc[j]);
            }
        }
    }
    if (valid) {
        float4* c4 = (float4*)(C + (size_t)row * HID + half * 32);
#pragma unroll
        for (int j = 0; j < 8; j++)
            c4[j] = make_float4(acc[4 * j], acc[4 * j + 1], acc[4 * j + 2], acc[4 * j + 3]);
    }
    int lane = threadIdx.x & 63;
    col_stats_butterfly32(acc, valid, lane, ldsr);
    __syncthreads();
    if (threadIdx.x < 64) {
        int c = threadIdx.x & 31;
        float v = ldsr[threadIdx.x];
        if (threadIdx.x < 32) atomicAdd(&rawOut[half * 32 + c], v);
        else                  atomicAdd(&rawOut[64 + half * 32 + c], v);
    }
}

// final small GEMM: C[n x NCOL] = act(A[n x 64]) @ W[64 x NCOL] + bias
template <int NCOL>
__global__ __launch_bounds__(256) void k_gemm_small(const float* __restrict__ A,
                                                    const float* __restrict__ rawIn, const float* __restrict__ g,
                                                    const float* __restrict__ b, float invN,
                                                    const float* __restrict__ W, const float* __restrict__ bias,
                                                    float* __restrict__ C, int n) {
    __shared__ float stl[2 * HID];
    if (threadIdx.x < HID) {
        float s, t;
        bn_fin(rawIn, g, b, invN, threadIdx.x, s, t);
        stl[threadIdx.x] = s;
        stl[HID + threadIdx.x] = t;
    }
    __syncthreads();
    int row = blockIdx.x * 256 + threadIdx.x;
    if (row >= n) return;
    float acc[NCOL];
#pragma unroll
    for (int j = 0; j < NCOL; j++) acc[j] = bias[j];
    const float4* a4 = (const float4*)(A + (size_t)row * HID);
    for (int kk = 0; kk < HID / 4; kk++) {
        float4 av = a4[kk];
        float a[4] = {av.x, av.y, av.z, av.w};
#pragma unroll
        for (int u = 0; u < 4; u++) {
            int k = kk * 4 + u;
            float xv = relu_aff(a[u], stl[k], stl[HID + k]);
#pragma unroll
            for (int j = 0; j < NCOL; j++) acc[j] = fmaf(xv, W[k * NCOL + j], acc[j]);
        }
    }
    float* c = C + (size_t)row * NCOL;
#pragma unroll
    for (int j = 0; j < NCOL; j++) c[j] = acc[j];
}

// ---------------- aggregation: o = (1+eps)*act(h) + sum act(h[src]) ----------------
template <bool DBL>
__global__ __launch_bounds__(256) void k_agg(const float* __restrict__ hb,
                                             const float* __restrict__ rawA, const float* __restrict__ gA,
                                             const float* __restrict__ bA,
                                             const float* __restrict__ rawB, const float* __restrict__ gB,
                                             const float* __restrict__ bB, float invN,
                                             const int* __restrict__ row_off, const int* __restrict__ col,
                                             const float* __restrict__ epsp, int li,
                                             float* __restrict__ o, int n) {
    int wid = threadIdx.x >> 6, lane = threadIdx.x & 63;
    int node = blockIdx.x * 4 + wid;
    if (node >= n) return;
    float sA, tA, sB = 0.f, tB = 0.f;
    bn_fin(rawA, gA, bA, invN, lane, sA, tA);
    if (DBL) bn_fin(rawB, gB, bB, invN, lane, sB, tB);
#define ACT(v) (DBL ? relu_aff(relu_aff((v), sA, tA), sB, tB) : relu_aff((v), sA, tA))
    float ope = 1.f + epsp[li];
    float acc = ope * ACT(hb[(size_t)node * HID + lane]);
    int e = row_off[node], b1 = row_off[node + 1];

    while (e + 8 <= b1) {
        int i0 = col[e], i1 = col[e + 1], i2 = col[e + 2], i3 = col[e + 3];
        int i4 = col[e + 4], i5 = col[e + 5], i6 = col[e + 6], i7 = col[e + 7];
        float v0 = hb[(size_t)i0 * HID + lane], v1 = hb[(size_t)i1 * HID + lane];
        float v2 = hb[(size_t)i2 * HID + lane], v3 = hb[(size_t)i3 * HID + lane];
        float v4 = hb[(size_t)i4 * HID + lane], v5 = hb[(size_t)i5 * HID + lane];
        float v6 = hb[(size_t)i6 * HID + lane], v7 = hb[(size_t)i7 * HID + lane];
        acc += ACT(v0) + ACT(v1) + ACT(v2) + ACT(v3);
        acc += ACT(v4) + ACT(v5) + ACT(v6) + ACT(v7);
        e += 8;
    }
    if (e + 4 <= b1) {
        int i0 = col[e], i1 = col[e + 1], i2 = col[e + 2], i3 = col[e + 3];
        float v0 = hb[(size_t)i0 * HID + lane], v1 = hb[(size_t)i1 * HID + lane];
        float v2 = hb[(size_t)i2 * HID + lane], v3 = hb[(size_t)i3 * HID + lane];
        acc += ACT(v0) + ACT(v1) + ACT(v2) + ACT(v3);
        e += 4;
    }
    if (e + 2 <= b1) {
        int i0 = col[e], i1 = col[e + 1];
        float v0 = hb[(size_t)i0 * HID + lane], v1 = hb[(size_t)i1 * HID + lane];
        acc += ACT(v0) + ACT(v1);
        e += 2;
    }
    if (e < b1) acc += ACT(hb[(size_t)col[e] * HID + lane]);
#undef ACT
    o[(size_t)node * HID + lane] = acc;
}

// read-only: stats of relu_aff(X; affine from rawIn,g,b) -> rawOut
__global__ __launch_bounds__(256) void k_poststats(const float* __restrict__ X,
                                                   const float* __restrict__ rawIn,
                                                   const float* __restrict__ g, const float* __restrict__ b,
                                                   float invN,
                                                   float* __restrict__ rawOut, long long n64) {
    long long stride = (long long)gridDim.x * 256;
    long long i0 = (long long)blockIdx.x * 256 + threadIdx.x;
    int col = threadIdx.x & 63;
    float sA, tA;
    bn_fin(rawIn, g, b, invN, col, sA, tA);
    float s = 0.f, q = 0.f;
    for (long long i = i0; i < n64; i += stride) {
        float v = relu_aff(X[i], sA, tA);
        s += v; q = fmaf(v, v, q);
    }
    __shared__ float ls[256], lq[256];
    ls[threadIdx.x] = s; lq[threadIdx.x] = q;
    __syncthreads();
    if (threadIdx.x < 64) {
        s = ls[threadIdx.x] + ls[threadIdx.x + 64] + ls[threadIdx.x + 128] + ls[threadIdx.x + 192];
        q = lq[threadIdx.x] + lq[threadIdx.x + 64] + lq[threadIdx.x + 128] + lq[threadIdx.x + 192];
        atomicAdd(&rawOut[col], s);
        atomicAdd(&rawOut[64 + col], q);
    }
}

extern "C" void kernel_launch(void* const* d_in, const int* in_sizes, int n_in,
                              void* d_out, int out_size, void* d_ws, size_t ws_size,
                              hipStream_t stream) {
    const float* x = (const float*)d_in[0];
    const int* ei = (const int*)d_in[1];
    const float* W_in = (const float*)d_in[2];
    const float* b_in = (const float*)d_in[3];
    const float* g_in = (const float*)d_in[4];
    const float* be_in = (const float*)d_in[5];
    const float* epsp = (const float*)d_in[6];
    const float* W1 = (const float*)d_in[7];
    const float* b1 = (const float*)d_in[8];
    const float* g1 = (const float*)d_in[9];
    const float* be1 = (const float*)d_in[10];
    const float* W2 = (const float*)d_in[11];
    const float* b2 = (const float*)d_in[12];
    const float* g2 = (const float*)d_in[13];
    const float* be2 = (const float*)d_in[14];
    const float* g_post = (const float*)d_in[15];
    const float* be_post = (const float*)d_in[16];
    const float* W_out1 = (const float*)d_in[17];
    const float* b_out1 = (const float*)d_in[18];
    const float* g_out = (const float*)d_in[19];
    const float* be_out = (const float*)d_in[20];
    const float* W_out2 = (const float*)d_in[21];
    const float* b_out2 = (const float*)d_in[22];

    const int N = in_sizes[0] / HID;
    const int E = in_sizes[1] / 2;
    const int* srcp = ei;
    const int* dstp = ei + E;

    size_t NODE = (size_t)N * HID;
    float* f = (float*)d_ws;
    float* pre0 = f;                 // stage-0 pre-BN (kept for concat)
    float* z0 = f + NODE;            // layer i pre-BN2 z (kept for concat)
    float* z1 = f + 2 * NODE;
    float* z2 = f + 3 * NODE;
    float* o = f + 4 * NODE;         // aggregation output
    float* p = f + 5 * NODE;         // gemm1 output / head pre-BN (reused)
    int* rc = (int*)(f + 6 * NODE);  // counts -> row offsets, N+1
    int* cursor = rc + (N + 1);
    int* col = cursor + N;           // E
    int* part = col + E;             // scan partials, <=512
    float* raw = (float*)(part + 512);  // 11 stages x {sum[64], sumsq[64]}

    size_t need = (size_t)(6 * NODE) * 4 + ((size_t)(N + 1) + N + E + 512) * 4 + (size_t)11 * 128 * 4;
    if (ws_size < need) return;  // fail loudly (output stays poisoned)

    float invN = 1.0f / (float)N;
    int nb = (N + 255) / 256;
    int gb = (N + 255) / 256;
    int eb = (E + 255) / 256;
    dim3 gb2(gb, 2);

    hipMemsetAsync(rc, 0, (size_t)(N + 1) * sizeof(int), stream);
    hipMemsetAsync(raw, 0, (size_t)11 * 128 * sizeof(float), stream);

    k_hist<<<eb, 256, 0, stream>>>(dstp, rc, E);
    k_scan1<<<nb, 256, 0, stream>>>(rc, part, N);
    k_scan2<<<1, 512, 0, stream>>>(part, nb, rc, N);
    k_scan3<<<nb, 256, 0, stream>>>(rc, part, rc, cursor, N);
    k_scatter<<<eb, 256, 0, stream>>>(srcp, dstp, cursor, col, E);

    // input projection + fused stats -> raw[0]
    k_gemm64h<false, true><<<gb2, 256, 0, stream>>>(x, nullptr, nullptr, nullptr, invN,
                                                    W_in, b_in, pre0, raw, N);

    float* zb[3] = {z0, z1, z2};
    for (int i = 0; i < LAYERS; i++) {
        int s1 = 1 + 3 * i, s2 = 2 + 3 * i, sp = 3 + 3 * i;
        const float* hb = (i == 0) ? pre0 : zb[i - 1];
        if (i == 0) {
            k_agg<false><<<(N + 3) / 4, 256, 0, stream>>>(hb, raw, g_in, be_in,
                                                          nullptr, nullptr, nullptr, invN,
                                                          rc, col, epsp, i, o, N);
        } else {
            int ps2 = 2 + 3 * (i - 1), psp = 3 + 3 * (i - 1);
            k_agg<true><<<(N + 3) / 4, 256, 0, stream>>>(hb,
                                                         raw + (size_t)ps2 * 128, g2 + (i - 1) * HID, be2 + (i - 1) * HID,
                                                         raw + (size_t)psp * 128, g_post + (i - 1) * HID, be_post + (i - 1) * HID,
                                                         invN, rc, col, epsp, i, o, N);
        }
        k_gemm64h<false, true><<<gb2, 256, 0, stream>>>(o, nullptr, nullptr, nullptr, invN,
                                                        W1 + (size_t)i * HID * HID, b1 + i * HID,
                                                        p, raw + (size_t)s1 * 128, N);
        k_gemm64h<true, true><<<gb2, 256, 0, stream>>>(p, raw + (size_t)s1 * 128, g1 + i * HID, be1 + i * HID, invN,
                                                       W2 + (size_t)i * HID * HID, b2 + i * HID,
                                                       zb[i], raw + (size_t)s2 * 128, N);
        k_poststats<<<512, 256, 0, stream>>>(zb[i], raw + (size_t)s2 * 128, g2 + i * HID, be2 + i * HID, invN,
                                             raw + (size_t)sp * 128, (long long)NODE);
    }

    // head: concat (double affines on the fly) -> 256x64 GEMM + stats -> 64x10 GEMM
    k_gemm_out1<<<gb2, 256, 0, stream>>>(pre0, z0, z1, z2,
                                         raw, g_in, be_in,
                                         raw + 2 * 128, g2, be2,
                                         raw + 3 * 128, g_post, be_post,
                                         invN, W_out1, b_out1, p, raw + 10 * 128, N);
    k_gemm_small<10><<<gb, 256, 0, stream>>>(p, raw + 10 * 128, g_out, be_out, invN,
                                             W_out2, b_out2, (float*)d_out, N);
}